// Round 20
// baseline (79.022 us; speedup 1.0000x reference)
//
#include <hip/hip_runtime.h>

typedef unsigned long long u64;
typedef unsigned int u32;

#define BDIM 16
#define NP   4096
#define NC   91
#define NCM1 90
#define MSEL 4096       // top-M per image (reference M)
#define NSORT 1024      // batch-0 sorted prefix size
#define KOUT 100
#define RSLOT 19        // max candidates per row (scores sum to 1, >0.05 => <=19)
#define CAP_D (NP * RSLOT)   // 77824: provable per-image max
#define SCORE_T 0.05f
#define NMS_T   0.5f
#define OFFSETF 10000.0f
#define DW_CLAMP_F 4.135166556742356f
#define WF 1333.0f
#define HF 800.0f
#define GTMIN 384        // early-exit floor for approx upper-set select
#define HCAP 4096        // per-image hot-array capacity (score >= 0.25)
#define FKEY (((u64)0x3E800000u) << 32)   // key of score 0.25 (flat=0)
#define HBASE 448        // hist bin base: bins (key>>53) in [490,508] provably

#define TN 1024
#define RPB 64            // rows per k_soft block (64 blocks per image)

// decode expressions (round-6..19 verified, byte-identical)
#define DECODE_BODY(kvar, bvar, BOXDST, PACKDST)                                   \
    {                                                                              \
        int flat = (int)(~(u32)(kvar));                                            \
        int nidx = flat / NCM1;                                                    \
        int c    = flat - nidx * NCM1 + 1;                                         \
        const float* pr = props + ((long)(bvar) * NP + nidx) * 4;                  \
        float x1 = pr[0], y1 = pr[1], x2 = pr[2], y2 = pr[3];                      \
        float w = x2 - x1, h = y2 - y1;                                            \
        float cx = x1 + 0.5f * w, cy = y1 + 0.5f * h;                              \
        const float* rr = boxreg + (((long)(bvar) * NP + nidx) * NC + c) * 4;      \
        float dx = rr[0] / 10.0f, dy = rr[1] / 10.0f;                              \
        float dw = fminf(rr[2] / 5.0f, DW_CLAMP_F);                                \
        float dh = fminf(rr[3] / 5.0f, DW_CLAMP_F);                                \
        float pcx = __fadd_rn(__fmul_rn(dx, w), cx);                               \
        float pcy = __fadd_rn(__fmul_rn(dy, h), cy);                               \
        float pw  = __fmul_rn(expf(dw), w);                                        \
        float ph2 = __fmul_rn(expf(dh), h);                                        \
        float bx1 = fminf(fmaxf(pcx - 0.5f * pw, 0.0f), WF);                       \
        float by1 = fminf(fmaxf(pcy - 0.5f * ph2, 0.0f), HF);                      \
        float bx2 = fminf(fmaxf(pcx + 0.5f * pw, 0.0f), WF);                       \
        float by2 = fminf(fmaxf(pcy + 0.5f * ph2, 0.0f), HF);                      \
        BOXDST = make_float4(bx1, by1, bx2, by2);                                  \
        float offB = (float)c * OFFSETF;                                           \
        float ox1 = bx1 + offB, oy1 = by1 + offB;                                  \
        float ox2 = bx2 + offB, oy2 = by2 + offB;                                  \
        PACKDST = make_float2((ox2 - ox1) * (oy2 - oy1), (float)c);                \
    }

// ---------------- Kernel 0: zero counters + per-image 64-bin histograms (1 block) ----------------
__global__ __launch_bounds__(1024) void k_zero(int* __restrict__ gcount,
                                               int* __restrict__ hcnt,
                                               int* __restrict__ ghist) {
    int t = threadIdx.x;
    if (t < BDIM) gcount[t] = 0;
    if (t >= 64 && t < 64 + BDIM) hcnt[t - 64] = 0;
    ghist[t] = 0;                       // 16*64 = 1024 exactly
}

// ---------------- Kernel 1: softmax -> dense + hot(score>=0.25) + 64-bin histogram ----------------
__global__ __launch_bounds__(256) void k_soft(const float* __restrict__ logits,
                                              u64* __restrict__ dense,
                                              int* __restrict__ gcount,
                                              u64* __restrict__ hot,
                                              int* __restrict__ hcnt,
                                              int* __restrict__ ghist) {
    __shared__ u64 stage[RPB * RSLOT];
    __shared__ u64 hstage[256];          // provable cap: <=4 per row
    __shared__ int lhist[64];
    __shared__ int s_cnt, s_base, s_hcnt, s_hbase;

    int blk  = blockIdx.x;
    int b    = blk >> 6;
    int lane = threadIdx.x & 63;
    int wid  = threadIdx.x >> 6;

    if (threadIdx.x == 0) { s_cnt = 0; s_hcnt = 0; }
    if (threadIdx.x < 64) lhist[threadIdx.x] = 0;
    __syncthreads();

    u64 lm = (1ull << lane) - 1ull;
    for (int it = 0; it < RPB / 4; ++it) {
        int row = blk * RPB + it * 4 + wid;
        const float* lg = logits + (long)row * NC;

        float v0 = lg[lane];
        float v1 = (lane < NC - 64) ? lg[64 + lane] : -3.0e38f;
        float mx = fmaxf(v0, v1);
#pragma unroll
        for (int s = 32; s; s >>= 1) mx = fmaxf(mx, __shfl_xor(mx, s));
        float e0 = expf(v0 - mx);
        float e1 = (lane < NC - 64) ? expf(v1 - mx) : 0.0f;
        float sum = e0 + e1;
#pragma unroll
        for (int s = 32; s; s >>= 1) sum += __shfl_xor(sum, s);

        float s0 = e0 / sum;
        float s1 = e1 / sum;

        int n = row & (NP - 1);
        bool p0 = (lane >= 1) && (s0 > SCORE_T);
        bool p1 = (lane < NC - 64) && (s1 > SCORE_T);
        u64 key0 = ((u64)__float_as_uint(s0) << 32) | (u32)(~(u32)(n * NCM1 + (lane - 1)));
        u64 key1 = ((u64)__float_as_uint(s1) << 32) | (u32)(~(u32)(n * NCM1 + (64 + lane - 1)));
        u64 m0 = __ballot(p0);
        u64 m1 = __ballot(p1);
        int c0  = __popcll(m0);
        int cnt = c0 + __popcll(m1);

        int base = 0;
        if (lane == 0 && cnt) base = atomicAdd(&s_cnt, cnt);
        base = __shfl(base, 0);
        if (p0) {
            stage[base + __popcll(m0 & lm)] = key0;
            atomicAdd(&lhist[(int)(key0 >> 53) - HBASE], 1);   // bins 490..508 provable
        }
        if (p1) {
            stage[base + c0 + __popcll(m1 & lm)] = key1;
            atomicAdd(&lhist[(int)(key1 >> 53) - HBASE], 1);
        }

        // hot subset: score >= 0.25 (<=4/row provable)
        bool q0 = p0 && (s0 >= 0.25f);
        bool q1 = p1 && (s1 >= 0.25f);
        u64 h0 = __ballot(q0);
        u64 h1 = __ballot(q1);
        int hc0 = __popcll(h0);
        int hrow = hc0 + __popcll(h1);
        int hb = 0;
        if (lane == 0 && hrow) hb = atomicAdd(&s_hcnt, hrow);
        hb = __shfl(hb, 0);
        if (q0) hstage[hb + __popcll(h0 & lm)] = key0;
        if (q1) hstage[hb + hc0 + __popcll(h1 & lm)] = key1;
    }
    __syncthreads();

    if (threadIdx.x == 0) {
        s_base  = atomicAdd(&gcount[b], s_cnt);
        s_hbase = atomicAdd(&hcnt[b], s_hcnt);
    }
    __syncthreads();
    int m = s_cnt, base = s_base;
    u64* kb = dense + (long)b * CAP_D + base;
    for (int i = threadIdx.x; i < m; i += 256) kb[i] = stage[i];
    int hm = s_hcnt, hb2 = s_hbase;
    u64* hbp = hot + (long)b * HCAP;
    for (int i = threadIdx.x; i < hm; i += 256) {
        int pos = hb2 + i;
        if (pos < HCAP) hbp[pos] = hstage[i];
    }
    if (threadIdx.x < 64) {
        int v = lhist[threadIdx.x];
        if (v) atomicAdd(&ghist[b * 64 + threadIdx.x], v);
    }
}

// ---------------- exact radix rank-select (round-8..19 verified body) ----------------
__device__ __forceinline__ u64 radix_rank(const u64* __restrict__ kb, int n, int rank,
                                          int* hist, int* p_sel, int* p_gt, int tid) {
    u64 prefix = 0, mask = 0;
    const int shifts[6] = {53, 42, 31, 20, 10, 0};
    const int bitsv [6] = {11, 11, 11, 11, 10, 10};

    for (int pass = 0; pass < 6; ++pass) {
        int shift = shifts[pass];
        int nb = 1 << bitsv[pass];
        if (tid < nb) hist[tid] = 0;
        if (tid + 1024 < nb) hist[tid + 1024] = 0;
        __syncthreads();
        for (int i = tid; i < n; i += 1024) {
            u64 k = kb[i];
            if ((k & mask) == prefix)
                atomicAdd(&hist[(int)((k >> shift) & (u64)(nb - 1))], 1);
        }
        __syncthreads();
        for (int d = 1; d < nb; d <<= 1) {
            int v0 = 0, v1 = 0;
            if (tid < nb && tid + d < nb) v0 = hist[tid + d];
            if (tid + 1024 < nb && tid + 1024 + d < nb) v1 = hist[tid + 1024 + d];
            __syncthreads();
            if (tid < nb) hist[tid] += v0;
            if (tid + 1024 < nb) hist[tid + 1024] += v1;
            __syncthreads();
        }
        for (int j = tid; j < nb; j += 1024) {
            int c  = hist[j];
            int cn = (j + 1 < nb) ? hist[j + 1] : 0;
            if (c >= rank && cn < rank) { *p_sel = j; *p_gt = cn; }
        }
        __syncthreads();
        prefix |= ((u64)(*p_sel)) << shift;
        mask   |= ((u64)(nb - 1)) << shift;
        rank   -= *p_gt;
        __syncthreads();
    }
    return prefix;
}

// ---------------- approx upper-set select over keys (round-16..19 verified; fallback only) ----------------
__device__ __forceinline__ u64 radix_upper(const u64* __restrict__ kb, int n, int rank,
                                           int* hist, int* p_sel, int* p_gt, int tid) {
    int rank0 = rank;
    u64 prefix = 0, mask = 0;
    const int shifts[6] = {53, 42, 31, 20, 10, 0};
    const int bitsv [6] = {11, 11, 11, 11, 10, 10};

    for (int pass = 0; pass < 6; ++pass) {
        int shift = shifts[pass];
        int nb = 1 << bitsv[pass];
        if (tid < nb) hist[tid] = 0;
        if (tid + 1024 < nb) hist[tid + 1024] = 0;
        __syncthreads();
        for (int i = tid; i < n; i += 1024) {
            u64 k = kb[i];
            if ((k & mask) == prefix)
                atomicAdd(&hist[(int)((k >> shift) & (u64)(nb - 1))], 1);
        }
        __syncthreads();
        for (int d = 1; d < nb; d <<= 1) {
            int v0 = 0, v1 = 0;
            if (tid < nb && tid + d < nb) v0 = hist[tid + d];
            if (tid + 1024 < nb && tid + 1024 + d < nb) v1 = hist[tid + 1024 + d];
            __syncthreads();
            if (tid < nb) hist[tid] += v0;
            if (tid + 1024 < nb) hist[tid + 1024] += v1;
            __syncthreads();
        }
        for (int j = tid; j < nb; j += 1024) {
            int c  = hist[j];
            int cn = (j + 1 < nb) ? hist[j + 1] : 0;
            if (c >= rank && cn < rank) { *p_sel = j; *p_gt = cn; }
        }
        __syncthreads();
        int sel = *p_sel, gt = *p_gt;
        rank -= gt;
        __syncthreads();
        if (pass < 5) {
            if (rank0 - rank >= GTMIN)
                return prefix + ((u64)(sel + 1) << shift);
            prefix |= ((u64)sel) << shift;
            mask   |= ((u64)(nb - 1)) << shift;
        } else {
            prefix |= ((u64)sel) << shift;
        }
    }
    return prefix;
}

// ---------------- Kernel 2: select + gather + sort -> sorted keys to ws (16 blocks) ----------------
__global__ __launch_bounds__(TN) void k_prep(const u64* __restrict__ dense,
                                             const int* __restrict__ gcount,
                                             const u64* __restrict__ hot,
                                             const int* __restrict__ hcnt,
                                             const int* __restrict__ ghist,
                                             u64* __restrict__ sk_ws,
                                             int* __restrict__ mb_ws,
                                             u64* __restrict__ bthr_ws) {
    __shared__ u64 skey[NSORT];
    __shared__ int hist[2048];
    __shared__ int s_cnt, s_sel, s_gt, s_found;

    int b = blockIdx.x, tid = threadIdx.x;
    int lane = tid & 63, wid = tid >> 6;
    int n = gcount[b]; if (n > CAP_D) n = CAP_D;
    const u64* kb = dense + (long)b * CAP_D;
    u64 lm = (1ull << lane) - 1ull;
    int npad = (n + TN - 1) & ~(TN - 1);

    // ---- Bthr via single-wave 64-bin scan (round-19 verified) ----
    u64 Bthr = 0ull;
    bool hist_ok = false;
    if (n > NSORT) {
        if (tid == 0) s_found = 0;
        __syncthreads();
        if (wid == 0) {
            int c = ghist[b * 64 + 63 - lane];          // lane l -> bin 511-l
            int cum = c;
#pragma unroll
            for (int s = 1; s < 64; s <<= 1) { int o = __shfl_up(cum, s); if (lane >= s) cum += o; }
            bool hit = (cum >= NSORT);
            u64 hm = __ballot(hit);
            if (hm) {
                int l0 = __builtin_ctzll(hm);
                if (lane == l0) { s_sel = 511 - l0; s_gt = cum - c; s_found = 1; }
            }
        }
        __syncthreads();
        if (s_found && s_gt >= GTMIN) { Bthr = ((u64)(s_sel + 1)) << 53; hist_ok = true; }
        else                          Bthr = radix_upper(kb, n, NSORT, hist, &s_sel, &s_gt, tid);
    }
    int hn = hcnt[b];
    bool use_hot = hist_ok && (Bthr >= FKEY) && (hn <= HCAP);

    // ---- gather batch-0: keys >= Bthr (verified aggregation pattern) ----
    skey[tid] = 0ull;
    if (tid == 0) s_cnt = 0;
    __syncthreads();
    if (use_hot) {
        const u64* hb = hot + (long)b * HCAP;
        int hpad = (hn + TN - 1) & ~(TN - 1);
        for (int i0 = tid; i0 < hpad; i0 += TN) {
            bool inb = (i0 < hn);
            u64 k = inb ? hb[i0] : 0ull;
            bool pred = inb && (k >= Bthr);
            u64 mb_ = __ballot(pred);
            int cnt = __popcll(mb_);
            int bp = 0;
            if (lane == 0 && cnt) bp = atomicAdd(&s_cnt, cnt);
            bp = __shfl(bp, 0);
            if (pred) {
                int pos = bp + __popcll(mb_ & lm);
                if (pos < NSORT) skey[pos] = k;
            }
        }
    } else {
        for (int i0 = tid; i0 < npad; i0 += TN) {
            bool inb = (i0 < n);
            u64 k = inb ? kb[i0] : 0ull;
            bool pred = inb && (k >= Bthr);
            u64 mb_ = __ballot(pred);
            int cnt = __popcll(mb_);
            int bp = 0;
            if (lane == 0 && cnt) bp = atomicAdd(&s_cnt, cnt);
            bp = __shfl(bp, 0);
            if (pred) {
                int pos = bp + __popcll(mb_ & lm);
                if (pos < NSORT) skey[pos] = k;
            }
        }
    }
    __syncthreads();
    if (s_cnt > NSORT) {    // safety: only if ghist corrupted -> exact recompute
        Bthr = radix_upper(kb, n, NSORT, hist, &s_sel, &s_gt, tid);
        skey[tid] = 0ull;
        if (tid == 0) s_cnt = 0;
        __syncthreads();
        for (int i0 = tid; i0 < npad; i0 += TN) {
            bool inb = (i0 < n);
            u64 k = inb ? kb[i0] : 0ull;
            bool pred = inb && (k >= Bthr);
            u64 mb_ = __ballot(pred);
            int cnt = __popcll(mb_);
            int bp = 0;
            if (lane == 0 && cnt) bp = atomicAdd(&s_cnt, cnt);
            bp = __shfl(bp, 0);
            if (pred) {
                int pos = bp + __popcll(mb_ & lm);
                if (pos < NSORT) skey[pos] = k;
            }
        }
        __syncthreads();
    }
    int mb = s_cnt; if (mb > NSORT) mb = NSORT;

    // ---- register bitonic sort desc over 1024 (round-8..19 verified) ----
    {
        u64 r = skey[tid];
        for (int kk = 2; kk <= NSORT; kk <<= 1) {
            for (int j = kk >> 1; j; j >>= 1) {
                u64 p;
                if (j >= 64) {
                    skey[tid] = r;
                    __syncthreads();
                    p = skey[tid ^ j];
                    __syncthreads();
                } else {
                    p = __shfl_xor(r, j);
                }
                bool lower = (tid & j) == 0;
                bool desc  = ((tid & kk) == 0);
                u64 mx = (r > p) ? r : p;
                u64 mn = (r > p) ? p : r;
                r = (lower == desc) ? mx : mn;
            }
        }
        sk_ws[b * NSORT + tid] = r;
    }
    if (tid == 0) { mb_ws[b] = mb; bthr_ws[b] = Bthr; }
}

// ---------------- Kernel 3: wide parallel decode of sorted keys (64 blocks) ----------------
__global__ __launch_bounds__(256) void k_dec(const u64* __restrict__ sk_ws,
                                             const int* __restrict__ mb_ws,
                                             const float* __restrict__ boxreg,
                                             const float* __restrict__ props,
                                             float4* __restrict__ box_ws,
                                             float2* __restrict__ pack_ws) {
    int b = blockIdx.y;
    int i = blockIdx.x * 256 + threadIdx.x;
    if (i >= mb_ws[b]) return;
    u64 k = sk_ws[b * NSORT + i];
    float4 bx; float2 pk;
    DECODE_BODY(k, b, bx, pk);
    box_ws[b * NSORT + i] = bx;
    pack_ws[b * NSORT + i] = pk;
}

// ---------------- Kernel 4: stage + serial walk + fallbacks + emit (16 blocks) ----------------
__global__ __launch_bounds__(TN) void k_walk(const u64* __restrict__ dense,
                                             const int* __restrict__ gcount,
                                             const u64* __restrict__ sk_ws,
                                             const int* __restrict__ mb_ws,
                                             const u64* __restrict__ bthr_ws,
                                             const float4* __restrict__ box_ws,
                                             const float2* __restrict__ pack_ws,
                                             const float* __restrict__ boxreg,
                                             const float* __restrict__ props,
                                             float* __restrict__ out) {
    __shared__ __align__(16) char ldsbuf[131072];   // aliased phases, 128 KB
    __shared__ int s_cnt, s_nacc, s_sel, s_gt;

    float4* sbox  = (float4*)ldsbuf;                // 16 KB (1024)
    float2* spack = (float2*)(ldsbuf + 16384);      //  8 KB
    u64*    skey  = (u64*)(ldsbuf + 24576);         //  8 KB
    int*    hist  = (int*)(ldsbuf + 32768);         //  8 KB (fallback radix scratch)

    int b = blockIdx.x, tid = threadIdx.x;
    int lane = tid & 63, wid = tid >> 6;
    int n = gcount[b]; if (n > CAP_D) n = CAP_D;
    u64 Bthr = bthr_ws[b];
    const u64* kb = dense + (long)b * CAP_D;
    u64 lm = (1ull << lane) - 1ull;
    int npad = (n + TN - 1) & ~(TN - 1);
    int mb = mb_ws[b];

    // ---- stage precomputed sorted keys/boxes into LDS (coalesced, parallel) ----
    skey[tid]  = sk_ws[b * NSORT + tid];
    sbox[tid]  = box_ws[b * NSORT + tid];
    spack[tid] = pack_ws[b * NSORT + tid];
    __syncthreads();

    // accepted list: wave-0 lane registers, 2 slots/lane (round-8..19 verified)
    float ax1_0 = 0, ay1_0 = 0, ax2_0 = 0, ay2_0 = 0, aar_0 = 0;
    float ax1_1 = 0, ay1_1 = 0, ax2_1 = 0, ay2_1 = 0, aar_1 = 0;
    int alb_0 = -1, alb_1 = -1;
    u64 aky_0 = 0, aky_1 = 0;
    int nacc = 0;

    // ---- serial walk in sorted order (round-8..19 verified text) ----
    if (wid == 0) {
        float4 Bv = sbox[0];
        float2 pk = spack[0];
        u64    ck = skey[0];
        for (int i = 0; i < mb && nacc < KOUT; ++i) {
            int ip = (i + 1 < mb) ? i + 1 : i;
            float4 nBv = sbox[ip];
            float2 npk = spack[ip];
            u64    nck = skey[ip];

            float areaB = pk.x;
            float labf  = pk.y;
            float off   = __fmul_rn(labf, OFFSETF);
            bool conf = false;
            if (lane < nacc && (float)alb_0 == labf) {
                float op1x = __fadd_rn(fminf(ax2_0, Bv.z), off);
                float op2x = __fadd_rn(fmaxf(ax1_0, Bv.x), off);
                float iw = fmaxf(op1x - op2x, 0.0f);
                float op1y = __fadd_rn(fminf(ay2_0, Bv.w), off);
                float op2y = __fadd_rn(fmaxf(ay1_0, Bv.y), off);
                float ih = fmaxf(op1y - op2y, 0.0f);
                float inter = iw * ih;
                float denom = areaB + aar_0 - inter + 1e-9f;
                if (inter / denom > NMS_T) conf = true;
            }
            if (64 + lane < nacc && (float)alb_1 == labf) {
                float op1x = __fadd_rn(fminf(ax2_1, Bv.z), off);
                float op2x = __fadd_rn(fmaxf(ax1_1, Bv.x), off);
                float iw = fmaxf(op1x - op2x, 0.0f);
                float op1y = __fadd_rn(fminf(ay2_1, Bv.w), off);
                float op2y = __fadd_rn(fmaxf(ay1_1, Bv.y), off);
                float ih = fmaxf(op1y - op2y, 0.0f);
                float inter = iw * ih;
                float denom = areaB + aar_1 - inter + 1e-9f;
                if (inter / denom > NMS_T) conf = true;
            }
            if (__ballot(conf) == 0ull) {
                if (nacc < 64) {
                    if (lane == nacc) {
                        ax1_0 = Bv.x; ay1_0 = Bv.y; ax2_0 = Bv.z; ay2_0 = Bv.w;
                        aar_0 = areaB; alb_0 = (int)labf; aky_0 = ck;
                    }
                } else {
                    if (lane == nacc - 64) {
                        ax1_1 = Bv.x; ay1_1 = Bv.y; ax2_1 = Bv.z; ay2_1 = Bv.w;
                        aar_1 = areaB; alb_1 = (int)labf; aky_1 = ck;
                    }
                }
                ++nacc;
            }
            Bv = nBv; pk = npk; ck = nck;
        }
        if (lane == 0) s_nacc = nacc;
    }
    __syncthreads();

    // ---- exact fallback: remaining ranks up to MSEL (rare; lazy exact T) ----
    if (s_nacc < KOUT && Bthr != 0ull) {
        u64 T = 0ull;
        if (n > MSEL) T = radix_rank(kb, n, MSEL, hist, &s_sel, &s_gt, tid);

        u64*    fkey  = (u64*)ldsbuf;               // 32 KB (4096)
        float4* fbox  = (float4*)(ldsbuf + 32768);  // 64 KB
        float2* fpack = (float2*)(ldsbuf + 98304);  // 32 KB

        for (int i = tid; i < MSEL; i += TN) fkey[i] = 0ull;
        if (tid == 0) s_cnt = 0;
        __syncthreads();
        for (int i0 = tid; i0 < npad; i0 += TN) {
            bool inb = (i0 < n);
            u64 k = inb ? kb[i0] : 0ull;
            bool pred = inb && (k >= T && k < Bthr);
            u64 mb_ = __ballot(pred);
            int cnt = __popcll(mb_);
            int bp = 0;
            if (lane == 0 && cnt) bp = atomicAdd(&s_cnt, cnt);
            bp = __shfl(bp, 0);
            if (pred) {
                int pos = bp + __popcll(mb_ & lm);
                if (pos < MSEL) fkey[pos] = k;
            }
        }
        __syncthreads();
        int mb2 = s_cnt; if (mb2 > MSEL) mb2 = MSEL;

        for (int kk = 2; kk <= MSEL; kk <<= 1) {
            for (int j = kk >> 1; j > 0; j >>= 1) {
                for (int t = tid; t < MSEL; t += TN) {
                    int l = t ^ j;
                    if (l > t) {
                        u64 a = fkey[t], c = fkey[l];
                        bool up = ((t & kk) == 0);
                        bool sw = up ? (a < c) : (a > c);
                        if (sw) { fkey[t] = c; fkey[l] = a; }
                    }
                }
                __syncthreads();
            }
        }

        for (int i = tid; i < mb2; i += TN) {
            u64 k = fkey[i];
            float4 bx; float2 pk;
            DECODE_BODY(k, b, bx, pk);
            fbox[i] = bx;
            fpack[i] = pk;
        }
        __syncthreads();

        if (wid == 0) {
            nacc = s_nacc;
            float4 Bv = fbox[0];
            float2 pk = fpack[0];
            u64    ck = fkey[0];
            for (int i = 0; i < mb2 && nacc < KOUT; ++i) {
                int ip = (i + 1 < mb2) ? i + 1 : i;
                float4 nBv = fbox[ip];
                float2 npk = fpack[ip];
                u64    nck = fkey[ip];

                float areaB = pk.x;
                float labf  = pk.y;
                float off   = __fmul_rn(labf, OFFSETF);
                bool conf = false;
                if (lane < nacc && (float)alb_0 == labf) {
                    float op1x = __fadd_rn(fminf(ax2_0, Bv.z), off);
                    float op2x = __fadd_rn(fmaxf(ax1_0, Bv.x), off);
                    float iw = fmaxf(op1x - op2x, 0.0f);
                    float op1y = __fadd_rn(fminf(ay2_0, Bv.w), off);
                    float op2y = __fadd_rn(fmaxf(ay1_0, Bv.y), off);
                    float ih = fmaxf(op1y - op2y, 0.0f);
                    float inter = iw * ih;
                    float denom = areaB + aar_0 - inter + 1e-9f;
                    if (inter / denom > NMS_T) conf = true;
                }
                if (64 + lane < nacc && (float)alb_1 == labf) {
                    float op1x = __fadd_rn(fminf(ax2_1, Bv.z), off);
                    float op2x = __fadd_rn(fmaxf(ax1_1, Bv.x), off);
                    float iw = fmaxf(op1x - op2x, 0.0f);
                    float op1y = __fadd_rn(fminf(ay2_1, Bv.w), off);
                    float op2y = __fadd_rn(fmaxf(ay1_1, Bv.y), off);
                    float ih = fmaxf(op1y - op2y, 0.0f);
                    float inter = iw * ih;
                    float denom = areaB + aar_1 - inter + 1e-9f;
                    if (inter / denom > NMS_T) conf = true;
                }
                if (__ballot(conf) == 0ull) {
                    if (nacc < 64) {
                        if (lane == nacc) {
                            ax1_0 = Bv.x; ay1_0 = Bv.y; ax2_0 = Bv.z; ay2_0 = Bv.w;
                            aar_0 = areaB; alb_0 = (int)labf; aky_0 = ck;
                        }
                    } else {
                        if (lane == nacc - 64) {
                            ax1_1 = Bv.x; ay1_1 = Bv.y; ax2_1 = Bv.z; ay2_1 = Bv.w;
                            aar_1 = areaB; alb_1 = (int)labf; aky_1 = ck;
                        }
                    }
                    ++nacc;
                }
                Bv = nBv; pk = npk; ck = nck;
            }
            if (lane == 0) s_nacc = nacc;
        }
        __syncthreads();
    }

    // ---- emit outputs in acceptance order (round-8..19 verified) ----
    int na = s_nacc; if (na > KOUT) na = KOUT;
    if (wid == 0) {
        if (lane < na) {
            int a = lane;
            float* ob = out + ((long)b * KOUT + a) * 4;
            ob[0] = ax1_0; ob[1] = ay1_0; ob[2] = ax2_0; ob[3] = ay2_0;
            out[BDIM * KOUT * 4 + b * KOUT + a] = __uint_as_float((u32)(aky_0 >> 32));
            out[BDIM * KOUT * 5 + b * KOUT + a] = (float)alb_0;
            out[BDIM * KOUT * 6 + b * KOUT + a] = 1.0f;
        }
        if (64 + lane < na) {
            int a = 64 + lane;
            float* ob = out + ((long)b * KOUT + a) * 4;
            ob[0] = ax1_1; ob[1] = ay1_1; ob[2] = ax2_1; ob[3] = ay2_1;
            out[BDIM * KOUT * 4 + b * KOUT + a] = __uint_as_float((u32)(aky_1 >> 32));
            out[BDIM * KOUT * 5 + b * KOUT + a] = (float)alb_1;
            out[BDIM * KOUT * 6 + b * KOUT + a] = 1.0f;
        }
    }
    for (int a = tid; a < KOUT; a += TN) {
        if (a >= na) {
            float* ob = out + ((long)b * KOUT + a) * 4;
            ob[0] = 0.0f; ob[1] = 0.0f; ob[2] = 0.0f; ob[3] = 0.0f;
            out[BDIM * KOUT * 4 + b * KOUT + a] = 0.0f;
            out[BDIM * KOUT * 5 + b * KOUT + a] = -1.0f;
            out[BDIM * KOUT * 6 + b * KOUT + a] = 0.0f;
        }
    }
}

extern "C" void kernel_launch(void* const* d_in, const int* in_sizes, int n_in,
                              void* d_out, int out_size, void* d_ws, size_t ws_size,
                              hipStream_t stream) {
    const float* logits = (const float*)d_in[0];
    const float* boxreg = (const float*)d_in[1];
    const float* props  = (const float*)d_in[2];
    float* out = (float*)d_out;

    char* ws = (char*)d_ws;
    int* gcount = (int*)(ws + 0);                 // 64 B
    int* hcnt   = (int*)(ws + 256);               // 64 B
    u64* bthr   = (u64*)(ws + 512);               // 128 B
    int* mb_ws  = (int*)(ws + 768);               // 64 B
    int* ghist  = (int*)(ws + 1024);              // 16*64*4 = 4 KB
    u64* sk_ws  = (u64*)(ws + 8192);              // 16*1024*8  = 128 KB
    float2* pack_ws = (float2*)(ws + 139264);     // 16*1024*8  = 128 KB
    float4* box_ws  = (float4*)(ws + 270336);     // 16*1024*16 = 256 KB
    u64* hot    = (u64*)(ws + 528384);            // 16*4096*8  = 512 KB
    u64* dense  = (u64*)(ws + 1048576);           // 16*77824*8 = 9.96 MB

    k_zero<<<1, 1024, 0, stream>>>(gcount, hcnt, ghist);
    k_soft<<<(BDIM * NP) / RPB, 256, 0, stream>>>(logits, dense, gcount, hot, hcnt, ghist);
    k_prep<<<BDIM, TN, 0, stream>>>(dense, gcount, hot, hcnt, ghist, sk_ws, mb_ws, bthr);
    k_dec<<<dim3(4, BDIM), 256, 0, stream>>>(sk_ws, mb_ws, boxreg, props, box_ws, pack_ws);
    k_walk<<<BDIM, TN, 0, stream>>>(dense, gcount, sk_ws, mb_ws, bthr,
                                    box_ws, pack_ws, boxreg, props, out);
}

// Round 22
// 77.041 us; speedup vs baseline: 1.0257x; 1.0257x over previous
//
#include <hip/hip_runtime.h>

typedef unsigned long long u64;
typedef unsigned int u32;

#define BDIM 16
#define NP   4096
#define NC   91
#define NCM1 90
#define MSEL 4096       // top-M per image (reference M)
#define NSORT 1024      // batch-0 sorted prefix size
#define KOUT 100
#define RSLOT 19        // max candidates per row (scores sum to 1, >0.05 => <=19)
#define CAP_D (NP * RSLOT)   // 77824: provable per-image max -> no overflow possible
#define SCORE_T 0.05f
#define NMS_T   0.5f
#define OFFSETF 10000.0f
#define DW_CLAMP_F 4.135166556742356f
#define WF 1333.0f
#define HF 800.0f
#define GTMIN 384        // early-exit floor for approx upper-set select
#define HCAP 4096        // per-image hot-array capacity (score >= 0.25)
#define FKEY (((u64)0x3E800000u) << 32)   // key of score 0.25 (flat=0)

#define TN 1024
#define RPB 64            // rows per k_soft block (64 blocks per image)

// decode expressions (round-6..18 verified, byte-identical)
#define DECODE_BODY(kvar, bvar, BOXDST, PACKDST)                                   \
    {                                                                              \
        int flat = (int)(~(u32)(kvar));                                            \
        int nidx = flat / NCM1;                                                    \
        int c    = flat - nidx * NCM1 + 1;                                         \
        const float* pr = props + ((long)(bvar) * NP + nidx) * 4;                  \
        float x1 = pr[0], y1 = pr[1], x2 = pr[2], y2 = pr[3];                      \
        float w = x2 - x1, h = y2 - y1;                                            \
        float cx = x1 + 0.5f * w, cy = y1 + 0.5f * h;                              \
        const float* rr = boxreg + (((long)(bvar) * NP + nidx) * NC + c) * 4;      \
        float dx = rr[0] / 10.0f, dy = rr[1] / 10.0f;                              \
        float dw = fminf(rr[2] / 5.0f, DW_CLAMP_F);                                \
        float dh = fminf(rr[3] / 5.0f, DW_CLAMP_F);                                \
        float pcx = __fadd_rn(__fmul_rn(dx, w), cx);                               \
        float pcy = __fadd_rn(__fmul_rn(dy, h), cy);                               \
        float pw  = __fmul_rn(expf(dw), w);                                        \
        float ph2 = __fmul_rn(expf(dh), h);                                        \
        float bx1 = fminf(fmaxf(pcx - 0.5f * pw, 0.0f), WF);                       \
        float by1 = fminf(fmaxf(pcy - 0.5f * ph2, 0.0f), HF);                      \
        float bx2 = fminf(fmaxf(pcx + 0.5f * pw, 0.0f), WF);                       \
        float by2 = fminf(fmaxf(pcy + 0.5f * ph2, 0.0f), HF);                      \
        BOXDST = make_float4(bx1, by1, bx2, by2);                                  \
        float offB = (float)c * OFFSETF;                                           \
        float ox1 = bx1 + offB, oy1 = by1 + offB;                                  \
        float ox2 = bx2 + offB, oy2 = by2 + offB;                                  \
        PACKDST = make_float2((ox2 - ox1) * (oy2 - oy1), (float)c);                \
    }

// ---------------- Kernel 0: zero counters + per-image histograms ----------------
__global__ __launch_bounds__(1024) void k_zero(int* __restrict__ gcount,
                                               int* __restrict__ hcnt,
                                               int* __restrict__ ghist) {
    int blk = blockIdx.x;
    if (blk == 0) {
        if (threadIdx.x < BDIM) gcount[threadIdx.x] = 0;
        if (threadIdx.x >= 64 && threadIdx.x < 64 + BDIM) hcnt[threadIdx.x - 64] = 0;
    } else {
        int* g = ghist + (blk - 1) * 2048;
        for (int i = threadIdx.x; i < 2048; i += 1024) g[i] = 0;
    }
}

// ---------------- Kernel 1: softmax -> dense + hot(score>=0.25) + score histogram ----------------
__global__ __launch_bounds__(256) void k_soft(const float* __restrict__ logits,
                                              u64* __restrict__ dense,
                                              int* __restrict__ gcount,
                                              u64* __restrict__ hot,
                                              int* __restrict__ hcnt,
                                              int* __restrict__ ghist) {
    __shared__ u64 stage[RPB * RSLOT];
    __shared__ u64 hstage[256];          // provable cap: <=4 per row (scores sum to 1)
    __shared__ int lhist[2048];
    __shared__ int s_cnt, s_base, s_hcnt, s_hbase;

    int blk  = blockIdx.x;
    int b    = blk >> 6;
    int lane = threadIdx.x & 63;
    int wid  = threadIdx.x >> 6;

    if (threadIdx.x == 0) { s_cnt = 0; s_hcnt = 0; }
    for (int i = threadIdx.x; i < 2048; i += 256) lhist[i] = 0;
    __syncthreads();

    u64 lm = (1ull << lane) - 1ull;
    for (int it = 0; it < RPB / 4; ++it) {
        int row = blk * RPB + it * 4 + wid;
        const float* lg = logits + (long)row * NC;

        float v0 = lg[lane];
        float v1 = (lane < NC - 64) ? lg[64 + lane] : -3.0e38f;
        float mx = fmaxf(v0, v1);
#pragma unroll
        for (int s = 32; s; s >>= 1) mx = fmaxf(mx, __shfl_xor(mx, s));
        float e0 = expf(v0 - mx);
        float e1 = (lane < NC - 64) ? expf(v1 - mx) : 0.0f;
        float sum = e0 + e1;
#pragma unroll
        for (int s = 32; s; s >>= 1) sum += __shfl_xor(sum, s);

        float s0 = e0 / sum;
        float s1 = e1 / sum;

        int n = row & (NP - 1);
        bool p0 = (lane >= 1) && (s0 > SCORE_T);
        bool p1 = (lane < NC - 64) && (s1 > SCORE_T);
        u64 key0 = ((u64)__float_as_uint(s0) << 32) | (u32)(~(u32)(n * NCM1 + (lane - 1)));
        u64 key1 = ((u64)__float_as_uint(s1) << 32) | (u32)(~(u32)(n * NCM1 + (64 + lane - 1)));
        u64 m0 = __ballot(p0);
        u64 m1 = __ballot(p1);
        int c0  = __popcll(m0);
        int cnt = c0 + __popcll(m1);

        int base = 0;
        if (lane == 0 && cnt) base = atomicAdd(&s_cnt, cnt);
        base = __shfl(base, 0);
        if (p0) {
            stage[base + __popcll(m0 & lm)] = key0;
            atomicAdd(&lhist[(int)(key0 >> 53)], 1);
        }
        if (p1) {
            stage[base + c0 + __popcll(m1 & lm)] = key1;
            atomicAdd(&lhist[(int)(key1 >> 53)], 1);
        }

        // hot subset: score >= 0.25 (<=4/row provable)
        bool q0 = p0 && (s0 >= 0.25f);
        bool q1 = p1 && (s1 >= 0.25f);
        u64 h0 = __ballot(q0);
        u64 h1 = __ballot(q1);
        int hc0 = __popcll(h0);
        int hrow = hc0 + __popcll(h1);
        int hb = 0;
        if (lane == 0 && hrow) hb = atomicAdd(&s_hcnt, hrow);
        hb = __shfl(hb, 0);
        if (q0) hstage[hb + __popcll(h0 & lm)] = key0;
        if (q1) hstage[hb + hc0 + __popcll(h1 & lm)] = key1;
    }
    __syncthreads();

    if (threadIdx.x == 0) {
        s_base  = atomicAdd(&gcount[b], s_cnt);
        s_hbase = atomicAdd(&hcnt[b], s_hcnt);
    }
    __syncthreads();
    int m = s_cnt, base = s_base;
    u64* kb = dense + (long)b * CAP_D + base;
    for (int i = threadIdx.x; i < m; i += 256) kb[i] = stage[i];
    int hm = s_hcnt, hb2 = s_hbase;
    u64* hbp = hot + (long)b * HCAP;
    for (int i = threadIdx.x; i < hm; i += 256) {
        int pos = hb2 + i;
        if (pos < HCAP) hbp[pos] = hstage[i];
    }
    for (int i = threadIdx.x; i < 2048; i += 256) {
        int v = lhist[i];
        if (v) atomicAdd(&ghist[b * 2048 + i], v);
    }
}

// ---------------- exact radix rank-select (round-8..18 verified body) ----------------
__device__ __forceinline__ u64 radix_rank(const u64* __restrict__ kb, int n, int rank,
                                          int* hist, int* p_sel, int* p_gt, int tid) {
    u64 prefix = 0, mask = 0;
    const int shifts[6] = {53, 42, 31, 20, 10, 0};
    const int bitsv [6] = {11, 11, 11, 11, 10, 10};

    for (int pass = 0; pass < 6; ++pass) {
        int shift = shifts[pass];
        int nb = 1 << bitsv[pass];
        if (tid < nb) hist[tid] = 0;
        if (tid + 1024 < nb) hist[tid + 1024] = 0;
        __syncthreads();
        for (int i = tid; i < n; i += 1024) {
            u64 k = kb[i];
            if ((k & mask) == prefix)
                atomicAdd(&hist[(int)((k >> shift) & (u64)(nb - 1))], 1);
        }
        __syncthreads();
        for (int d = 1; d < nb; d <<= 1) {
            int v0 = 0, v1 = 0;
            if (tid < nb && tid + d < nb) v0 = hist[tid + d];
            if (tid + 1024 < nb && tid + 1024 + d < nb) v1 = hist[tid + 1024 + d];
            __syncthreads();
            if (tid < nb) hist[tid] += v0;
            if (tid + 1024 < nb) hist[tid + 1024] += v1;
            __syncthreads();
        }
        for (int j = tid; j < nb; j += 1024) {
            int c  = hist[j];
            int cn = (j + 1 < nb) ? hist[j + 1] : 0;
            if (c >= rank && cn < rank) { *p_sel = j; *p_gt = cn; }
        }
        __syncthreads();
        prefix |= ((u64)(*p_sel)) << shift;
        mask   |= ((u64)(nb - 1)) << shift;
        rank   -= *p_gt;
        __syncthreads();
    }
    return prefix;
}

// ---------------- approx upper-set select over keys (round-16/17 verified; fallback only) ----------------
__device__ __forceinline__ u64 radix_upper(const u64* __restrict__ kb, int n, int rank,
                                           int* hist, int* p_sel, int* p_gt, int tid) {
    int rank0 = rank;
    u64 prefix = 0, mask = 0;
    const int shifts[6] = {53, 42, 31, 20, 10, 0};
    const int bitsv [6] = {11, 11, 11, 11, 10, 10};

    for (int pass = 0; pass < 6; ++pass) {
        int shift = shifts[pass];
        int nb = 1 << bitsv[pass];
        if (tid < nb) hist[tid] = 0;
        if (tid + 1024 < nb) hist[tid + 1024] = 0;
        __syncthreads();
        for (int i = tid; i < n; i += 1024) {
            u64 k = kb[i];
            if ((k & mask) == prefix)
                atomicAdd(&hist[(int)((k >> shift) & (u64)(nb - 1))], 1);
        }
        __syncthreads();
        for (int d = 1; d < nb; d <<= 1) {
            int v0 = 0, v1 = 0;
            if (tid < nb && tid + d < nb) v0 = hist[tid + d];
            if (tid + 1024 < nb && tid + 1024 + d < nb) v1 = hist[tid + 1024 + d];
            __syncthreads();
            if (tid < nb) hist[tid] += v0;
            if (tid + 1024 < nb) hist[tid + 1024] += v1;
            __syncthreads();
        }
        for (int j = tid; j < nb; j += 1024) {
            int c  = hist[j];
            int cn = (j + 1 < nb) ? hist[j + 1] : 0;
            if (c >= rank && cn < rank) { *p_sel = j; *p_gt = cn; }
        }
        __syncthreads();
        int sel = *p_sel, gt = *p_gt;
        rank -= gt;
        __syncthreads();
        if (pass < 5) {
            if (rank0 - rank >= GTMIN)
                return prefix + ((u64)(sel + 1) << shift);
            prefix |= ((u64)sel) << shift;
            mask   |= ((u64)(nb - 1)) << shift;
        } else {
            prefix |= ((u64)sel) << shift;
        }
    }
    return prefix;
}

// ---------------- Kernel 2: fused select(wave-scan hist) + gather(hot) + sort + decode + walk ----------------
__global__ __launch_bounds__(TN) void k_post(const u64* __restrict__ dense,
                                             const int* __restrict__ gcount,
                                             const u64* __restrict__ hot,
                                             const int* __restrict__ hcnt,
                                             const int* __restrict__ ghist,
                                             const float* __restrict__ boxreg,
                                             const float* __restrict__ props,
                                             float* __restrict__ out) {
    __shared__ __align__(16) char ldsbuf[131072];   // aliased phases, 128 KB
    __shared__ int s_cnt, s_nacc, s_sel, s_gt, s_found;

    // batch-0 layout
    float4* sbox  = (float4*)ldsbuf;                // 16 KB (1024)
    float2* spack = (float2*)(ldsbuf + 16384);      //  8 KB
    u64*    skey  = (u64*)(ldsbuf + 24576);         //  8 KB
    int*    hist  = (int*)(ldsbuf + 32768);         //  8 KB (fallback radix scratch)

    int b = blockIdx.x, tid = threadIdx.x;
    int lane = tid & 63, wid = tid >> 6;
    int n = gcount[b]; if (n > CAP_D) n = CAP_D;
    const u64* kb = dense + (long)b * CAP_D;
    u64 lm = (1ull << lane) - 1ull;
    int npad = (n + TN - 1) & ~(TN - 1);

    // ---- Bthr via single-wave 64-bin scan (scores in (0.05,1] -> bins 490..508 ⊂ [448,511]) ----
    u64 Bthr = 0ull;
    bool hist_ok = false;
    if (n > NSORT) {
        if (tid == 0) s_found = 0;
        __syncthreads();
        if (wid == 0) {
            int c = ghist[b * 2048 + 511 - lane];      // lane l -> bin 511-l (descending)
            int cum = c;
#pragma unroll
            for (int s = 1; s < 64; s <<= 1) { int o = __shfl_up(cum, s); if (lane >= s) cum += o; }
            bool hit = (cum >= NSORT);
            u64 hm = __ballot(hit);
            if (hm) {
                int l0 = __builtin_ctzll(hm);          // first crossing (highest bin)
                if (lane == l0) { s_sel = 511 - l0; s_gt = cum - c; s_found = 1; }
            }
        }
        __syncthreads();
        if (s_found && s_gt >= GTMIN) { Bthr = ((u64)(s_sel + 1)) << 53; hist_ok = true; }
        else                          Bthr = radix_upper(kb, n, NSORT, hist, &s_sel, &s_gt, tid);
    }
    int hn = hcnt[b];
    bool use_hot = hist_ok && (Bthr >= FKEY) && (hn <= HCAP);

    // ---- gather batch-0: keys >= Bthr (verified aggregation pattern) ----
    skey[tid] = 0ull;
    if (tid == 0) s_cnt = 0;
    __syncthreads();
    if (use_hot) {
        const u64* hb = hot + (long)b * HCAP;
        int hpad = (hn + TN - 1) & ~(TN - 1);
        for (int i0 = tid; i0 < hpad; i0 += TN) {
            bool inb = (i0 < hn);
            u64 k = inb ? hb[i0] : 0ull;
            bool pred = inb && (k >= Bthr);
            u64 mb_ = __ballot(pred);
            int cnt = __popcll(mb_);
            int bp = 0;
            if (lane == 0 && cnt) bp = atomicAdd(&s_cnt, cnt);
            bp = __shfl(bp, 0);
            if (pred) {
                int pos = bp + __popcll(mb_ & lm);
                if (pos < NSORT) skey[pos] = k;
            }
        }
    } else {
        for (int i0 = tid; i0 < npad; i0 += TN) {
            bool inb = (i0 < n);
            u64 k = inb ? kb[i0] : 0ull;
            bool pred = inb && (k >= Bthr);
            u64 mb_ = __ballot(pred);
            int cnt = __popcll(mb_);
            int bp = 0;
            if (lane == 0 && cnt) bp = atomicAdd(&s_cnt, cnt);
            bp = __shfl(bp, 0);
            if (pred) {
                int pos = bp + __popcll(mb_ & lm);
                if (pos < NSORT) skey[pos] = k;
            }
        }
    }
    __syncthreads();
    if (s_cnt > NSORT) {    // safety: only if ghist corrupted -> exact recompute
        Bthr = radix_upper(kb, n, NSORT, hist, &s_sel, &s_gt, tid);
        skey[tid] = 0ull;
        if (tid == 0) s_cnt = 0;
        __syncthreads();
        for (int i0 = tid; i0 < npad; i0 += TN) {
            bool inb = (i0 < n);
            u64 k = inb ? kb[i0] : 0ull;
            bool pred = inb && (k >= Bthr);
            u64 mb_ = __ballot(pred);
            int cnt = __popcll(mb_);
            int bp = 0;
            if (lane == 0 && cnt) bp = atomicAdd(&s_cnt, cnt);
            bp = __shfl(bp, 0);
            if (pred) {
                int pos = bp + __popcll(mb_ & lm);
                if (pos < NSORT) skey[pos] = k;
            }
        }
        __syncthreads();
    }
    int mb = s_cnt; if (mb > NSORT) mb = NSORT;

    // ---- register bitonic sort desc over 1024 (round-8..18 verified) ----
    {
        u64 r = skey[tid];
        for (int kk = 2; kk <= NSORT; kk <<= 1) {
            for (int j = kk >> 1; j; j >>= 1) {
                u64 p;
                if (j >= 64) {
                    skey[tid] = r;
                    __syncthreads();
                    p = skey[tid ^ j];
                    __syncthreads();
                } else {
                    p = __shfl_xor(r, j);
                }
                bool lower = (tid & j) == 0;
                bool desc  = ((tid & kk) == 0);
                u64 mx = (r > p) ? r : p;
                u64 mn = (r > p) ? p : r;
                r = (lower == desc) ? mx : mn;
            }
        }
        skey[tid] = r;
        __syncthreads();
    }

    // ---- decode sorted candidates ----
    for (int i = tid; i < mb; i += TN) {
        u64 k = skey[i];
        float4 bx; float2 pk;
        DECODE_BODY(k, b, bx, pk);
        sbox[i] = bx;
        spack[i] = pk;
    }
    __syncthreads();

    // accepted list: wave-0 lane registers, 2 slots/lane (round-8..18 verified)
    float ax1_0 = 0, ay1_0 = 0, ax2_0 = 0, ay2_0 = 0, aar_0 = 0;
    float ax1_1 = 0, ay1_1 = 0, ax2_1 = 0, ay2_1 = 0, aar_1 = 0;
    int alb_0 = -1, alb_1 = -1;
    u64 aky_0 = 0, aky_1 = 0;
    int nacc = 0;

    // ---- serial walk in sorted order (round-8..17 verified text) ----
    if (wid == 0) {
        float4 Bv = sbox[0];
        float2 pk = spack[0];
        u64    ck = skey[0];
        for (int i = 0; i < mb && nacc < KOUT; ++i) {
            int ip = (i + 1 < mb) ? i + 1 : i;
            float4 nBv = sbox[ip];
            float2 npk = spack[ip];
            u64    nck = skey[ip];

            float areaB = pk.x;
            float labf  = pk.y;
            float off   = __fmul_rn(labf, OFFSETF);
            bool conf = false;
            if (lane < nacc && (float)alb_0 == labf) {
                float op1x = __fadd_rn(fminf(ax2_0, Bv.z), off);
                float op2x = __fadd_rn(fmaxf(ax1_0, Bv.x), off);
                float iw = fmaxf(op1x - op2x, 0.0f);
                float op1y = __fadd_rn(fminf(ay2_0, Bv.w), off);
                float op2y = __fadd_rn(fmaxf(ay1_0, Bv.y), off);
                float ih = fmaxf(op1y - op2y, 0.0f);
                float inter = iw * ih;
                float denom = areaB + aar_0 - inter + 1e-9f;
                if (inter / denom > NMS_T) conf = true;
            }
            if (64 + lane < nacc && (float)alb_1 == labf) {
                float op1x = __fadd_rn(fminf(ax2_1, Bv.z), off);
                float op2x = __fadd_rn(fmaxf(ax1_1, Bv.x), off);
                float iw = fmaxf(op1x - op2x, 0.0f);
                float op1y = __fadd_rn(fminf(ay2_1, Bv.w), off);
                float op2y = __fadd_rn(fmaxf(ay1_1, Bv.y), off);
                float ih = fmaxf(op1y - op2y, 0.0f);
                float inter = iw * ih;
                float denom = areaB + aar_1 - inter + 1e-9f;
                if (inter / denom > NMS_T) conf = true;
            }
            if (__ballot(conf) == 0ull) {
                if (nacc < 64) {
                    if (lane == nacc) {
                        ax1_0 = Bv.x; ay1_0 = Bv.y; ax2_0 = Bv.z; ay2_0 = Bv.w;
                        aar_0 = areaB; alb_0 = (int)labf; aky_0 = ck;
                    }
                } else {
                    if (lane == nacc - 64) {
                        ax1_1 = Bv.x; ay1_1 = Bv.y; ax2_1 = Bv.z; ay2_1 = Bv.w;
                        aar_1 = areaB; alb_1 = (int)labf; aky_1 = ck;
                    }
                }
                ++nacc;
            }
            Bv = nBv; pk = npk; ck = nck;
        }
        if (lane == 0) s_nacc = nacc;
    }
    __syncthreads();

    // ---- exact fallback: remaining ranks up to MSEL (rare; lazy exact T) ----
    if (s_nacc < KOUT && Bthr != 0ull) {
        u64 T = 0ull;
        if (n > MSEL) T = radix_rank(kb, n, MSEL, hist, &s_sel, &s_gt, tid);

        u64*    fkey  = (u64*)ldsbuf;               // 32 KB (4096)
        float4* fbox  = (float4*)(ldsbuf + 32768);  // 64 KB
        float2* fpack = (float2*)(ldsbuf + 98304);  // 32 KB

        for (int i = tid; i < MSEL; i += TN) fkey[i] = 0ull;
        if (tid == 0) s_cnt = 0;
        __syncthreads();
        for (int i0 = tid; i0 < npad; i0 += TN) {
            bool inb = (i0 < n);
            u64 k = inb ? kb[i0] : 0ull;
            bool pred = inb && (k >= T && k < Bthr);
            u64 mb_ = __ballot(pred);
            int cnt = __popcll(mb_);
            int bp = 0;
            if (lane == 0 && cnt) bp = atomicAdd(&s_cnt, cnt);
            bp = __shfl(bp, 0);
            if (pred) {
                int pos = bp + __popcll(mb_ & lm);
                if (pos < MSEL) fkey[pos] = k;
            }
        }
        __syncthreads();
        int mb2 = s_cnt; if (mb2 > MSEL) mb2 = MSEL;

        for (int kk = 2; kk <= MSEL; kk <<= 1) {
            for (int j = kk >> 1; j > 0; j >>= 1) {
                for (int t = tid; t < MSEL; t += TN) {
                    int l = t ^ j;
                    if (l > t) {
                        u64 a = fkey[t], c = fkey[l];
                        bool up = ((t & kk) == 0);
                        bool sw = up ? (a < c) : (a > c);
                        if (sw) { fkey[t] = c; fkey[l] = a; }
                    }
                }
                __syncthreads();
            }
        }

        for (int i = tid; i < mb2; i += TN) {
            u64 k = fkey[i];
            float4 bx; float2 pk;
            DECODE_BODY(k, b, bx, pk);
            fbox[i] = bx;
            fpack[i] = pk;
        }
        __syncthreads();

        if (wid == 0) {
            nacc = s_nacc;
            float4 Bv = fbox[0];
            float2 pk = fpack[0];
            u64    ck = fkey[0];
            for (int i = 0; i < mb2 && nacc < KOUT; ++i) {
                int ip = (i + 1 < mb2) ? i + 1 : i;
                float4 nBv = fbox[ip];
                float2 npk = fpack[ip];
                u64    nck = fkey[ip];

                float areaB = pk.x;
                float labf  = pk.y;
                float off   = __fmul_rn(labf, OFFSETF);
                bool conf = false;
                if (lane < nacc && (float)alb_0 == labf) {
                    float op1x = __fadd_rn(fminf(ax2_0, Bv.z), off);
                    float op2x = __fadd_rn(fmaxf(ax1_0, Bv.x), off);
                    float iw = fmaxf(op1x - op2x, 0.0f);
                    float op1y = __fadd_rn(fminf(ay2_0, Bv.w), off);
                    float op2y = __fadd_rn(fmaxf(ay1_0, Bv.y), off);
                    float ih = fmaxf(op1y - op2y, 0.0f);
                    float inter = iw * ih;
                    float denom = areaB + aar_0 - inter + 1e-9f;
                    if (inter / denom > NMS_T) conf = true;
                }
                if (64 + lane < nacc && (float)alb_1 == labf) {
                    float op1x = __fadd_rn(fminf(ax2_1, Bv.z), off);
                    float op2x = __fadd_rn(fmaxf(ax1_1, Bv.x), off);
                    float iw = fmaxf(op1x - op2x, 0.0f);
                    float op1y = __fadd_rn(fminf(ay2_1, Bv.w), off);
                    float op2y = __fadd_rn(fmaxf(ay1_1, Bv.y), off);
                    float ih = fmaxf(op1y - op2y, 0.0f);
                    float inter = iw * ih;
                    float denom = areaB + aar_1 - inter + 1e-9f;
                    if (inter / denom > NMS_T) conf = true;
                }
                if (__ballot(conf) == 0ull) {
                    if (nacc < 64) {
                        if (lane == nacc) {
                            ax1_0 = Bv.x; ay1_0 = Bv.y; ax2_0 = Bv.z; ay2_0 = Bv.w;
                            aar_0 = areaB; alb_0 = (int)labf; aky_0 = ck;
                        }
                    } else {
                        if (lane == nacc - 64) {
                            ax1_1 = Bv.x; ay1_1 = Bv.y; ax2_1 = Bv.z; ay2_1 = Bv.w;
                            aar_1 = areaB; alb_1 = (int)labf; aky_1 = ck;
                        }
                    }
                    ++nacc;
                }
                Bv = nBv; pk = npk; ck = nck;
            }
            if (lane == 0) s_nacc = nacc;
        }
        __syncthreads();
    }

    // ---- emit outputs in acceptance order (round-8..18 verified) ----
    int na = s_nacc; if (na > KOUT) na = KOUT;
    if (wid == 0) {
        if (lane < na) {
            int a = lane;
            float* ob = out + ((long)b * KOUT + a) * 4;
            ob[0] = ax1_0; ob[1] = ay1_0; ob[2] = ax2_0; ob[3] = ay2_0;
            out[BDIM * KOUT * 4 + b * KOUT + a] = __uint_as_float((u32)(aky_0 >> 32));
            out[BDIM * KOUT * 5 + b * KOUT + a] = (float)alb_0;
            out[BDIM * KOUT * 6 + b * KOUT + a] = 1.0f;
        }
        if (64 + lane < na) {
            int a = 64 + lane;
            float* ob = out + ((long)b * KOUT + a) * 4;
            ob[0] = ax1_1; ob[1] = ay1_1; ob[2] = ax2_1; ob[3] = ay2_1;
            out[BDIM * KOUT * 4 + b * KOUT + a] = __uint_as_float((u32)(aky_1 >> 32));
            out[BDIM * KOUT * 5 + b * KOUT + a] = (float)alb_1;
            out[BDIM * KOUT * 6 + b * KOUT + a] = 1.0f;
        }
    }
    for (int a = tid; a < KOUT; a += TN) {
        if (a >= na) {
            float* ob = out + ((long)b * KOUT + a) * 4;
            ob[0] = 0.0f; ob[1] = 0.0f; ob[2] = 0.0f; ob[3] = 0.0f;
            out[BDIM * KOUT * 4 + b * KOUT + a] = 0.0f;
            out[BDIM * KOUT * 5 + b * KOUT + a] = -1.0f;
            out[BDIM * KOUT * 6 + b * KOUT + a] = 0.0f;
        }
    }
}

extern "C" void kernel_launch(void* const* d_in, const int* in_sizes, int n_in,
                              void* d_out, int out_size, void* d_ws, size_t ws_size,
                              hipStream_t stream) {
    const float* logits = (const float*)d_in[0];
    const float* boxreg = (const float*)d_in[1];
    const float* props  = (const float*)d_in[2];
    float* out = (float*)d_out;

    char* ws = (char*)d_ws;
    int* gcount = (int*)(ws + 0);                 // 64 B
    int* hcnt   = (int*)(ws + 256);               // 64 B
    int* ghist  = (int*)(ws + 1024);              // 16*2048*4 = 128 KB
    u64* hot    = (u64*)(ws + 132096);            // 16*4096*8 = 512 KB
    u64* dense  = (u64*)(ws + 1048576);           // 16*77824*8 = 9.96 MB

    k_zero<<<17, 1024, 0, stream>>>(gcount, hcnt, ghist);
    k_soft<<<(BDIM * NP) / RPB, 256, 0, stream>>>(logits, dense, gcount, hot, hcnt, ghist);
    k_post<<<BDIM, TN, 0, stream>>>(dense, gcount, hot, hcnt, ghist, boxreg, props, out);
}